// Round 6
// baseline (154.391 us; speedup 1.0000x reference)
//
#include <hip/hip_runtime.h>
#include <hip/hip_bf16.h>
#include <stdint.h>

#define B_DIM   4096
#define IN_DIM  512
#define OUT_DIM 512
#define M_DIM   16
#define K_DIM   (IN_DIM * M_DIM)     // 8192
#define MN      (B_DIM * OUT_DIM)    // 2097152

typedef unsigned short ushort_t;
typedef __attribute__((ext_vector_type(8))) __bf16 bf16x8;
typedef __attribute__((ext_vector_type(2))) __bf16 bf16x2;
typedef __attribute__((ext_vector_type(4))) float  f32x4;

__device__ __forceinline__ ushort_t f2bf(float f) {
  union { float f; uint32_t u; } v; v.f = f;
  uint32_t u = v.u + 0x7fffu + ((v.u >> 16) & 1u);   // RNE
  return (ushort_t)(u >> 16);
}

// pack two floats -> one u32 of 2 x bf16 (compiler emits v_cvt_pk_bf16_f32)
__device__ __forceinline__ uint32_t pkbf(float lo, float hi) {
  union { bf16x2 h; uint32_t u; } v;
  v.h[0] = (__bf16)lo; v.h[1] = (__bf16)hi;
  return v.u;
}

// force a wave-uniform float into an SGPR
__device__ __forceinline__ float rfl(float f) {
  union { float f; int i; } v; v.f = f;
  v.i = __builtin_amdgcn_readfirstlane(v.i);
  return v.f;
}

// ---------- phase 1: coeffs fp32 -> bf16 (layout [OUT][IN][M] == B^T [N][K]) ----------
#define CONV_N4 (OUT_DIM * K_DIM / 4)
__global__ __launch_bounds__(256) void convert_coeffs_kernel(
    const float* __restrict__ src, ushort_t* __restrict__ dst) {
  int i = blockIdx.x * 256 + threadIdx.x;
  float4 v = ((const float4*)src)[i];
  ushort4 o;
  o.x = f2bf(v.x); o.y = f2bf(v.y); o.z = f2bf(v.z); o.w = f2bf(v.w);
  ((ushort4*)dst)[i] = o;
}

// ---------- phase 2: FUSED basis+GEMM, 2 blocks/CU for cross-block overlap ----------
#define BM 128
#define BN 256
#define BK 32                 // = 2 input-columns x 16 m
#define SPLITK 8
#define KC (K_DIM / SPLITK)   // 1024
#define NITER (KC / BK)       // 32 K-steps
#define XCOLS (KC / M_DIM)    // 64 x-columns per block

#define GLD16(g, l) \
  __builtin_amdgcn_global_load_lds((const __attribute__((address_space(1))) void*)(g), \
                                   (__attribute__((address_space(3))) void*)(l), 16, 0, 0)

template <int ATOMIC>
__global__ __launch_bounds__(256, 2) void gemm_kernel(
    const float* __restrict__ x,      // [B_DIM][IN_DIM] fp32
    const ushort_t* __restrict__ Bt,  // coeffs bf16 [OUT_DIM][K_DIM]
    const float* __restrict__ bc,     // [16][8]
    float* __restrict__ P) {          // partials [SPLITK][B][OUT] or out
  // LDS total = 16K + 32K + 32K = 80 KiB exactly -> 2 blocks per 160 KiB CU
  __shared__ __align__(16) ushort_t As[2][BM * BK];     // 2 x 8 KiB
  __shared__ __align__(16) ushort_t Bs[2][BN * BK];     // 2 x 16 KiB
  __shared__ __align__(16) float    Xs[XCOLS * BM];     // 32 KiB, [col][row], stride 128
  const int tid  = threadIdx.x;
  const int wave = tid >> 6;
  const int lane = tid & 63;
  const int wgid = blockIdx.x;
  const int ks = wgid & 7, bn = (wgid >> 3) & 1, bm = wgid >> 4;  // same-ks -> same XCD

  // ---- x-tile staging (one-time): coalesced float4 loads -> transposed LDS ----
  // thread t: row r = t>>1, half hf = t&1 covers cols hf*32 .. hf*32+31
  {
    const int r = tid >> 1, hf = tid & 1;
    const float4* xr4 = (const float4*)(x + (size_t)(bm * BM + r) * IN_DIM + ks * XCOLS + hf * 32);
    #pragma unroll
    for (int j = 0; j < 8; ++j) {
      float4 v = xr4[j];
      Xs[(hf * 32 + j * 4 + 0) * BM + r] = v.x;
      Xs[(hf * 32 + j * 4 + 1) * BM + r] = v.y;
      Xs[(hf * 32 + j * 4 + 2) * BM + r] = v.z;
      Xs[(hf * 32 + j * 4 + 3) * BM + r] = v.w;
    }
  }

  // ---- B staging: global_load_lds linear dest, pre-swizzled source slot ----
  // each wave: 4 GLD16 cover rows {w*16..w*16+15} + {64,128,192}
  const int srow = wave * 16 + (lane >> 2);
  const int scol = (((lane & 3) ^ ((lane >> 3) & 3)) * 8);
  const ushort_t* Bg0 = Bt + (size_t)(bn * BN + srow) * K_DIM + ks * KC + scol;
  const ushort_t* Bg1 = Bg0 + (size_t)64  * K_DIM;
  const ushort_t* Bg2 = Bg0 + (size_t)128 * K_DIM;
  const ushort_t* Bg3 = Bg0 + (size_t)192 * K_DIM;
  const int bofs0 = (wave * 16) * BK;
  const int bofs1 = (64  + wave * 16) * BK;
  const int bofs2 = (128 + wave * 16) * BK;
  const int bofs3 = (192 + wave * 16) * BK;

#define STAGEB(b) do { \
    GLD16(Bg0, &Bs[b][bofs0]); GLD16(Bg1, &Bs[b][bofs1]); \
    GLD16(Bg2, &Bs[b][bofs2]); GLD16(Bg3, &Bs[b][bofs3]); \
    Bg0 += BK; Bg1 += BK; Bg2 += BK; Bg3 += BK; } while (0)

  // ---- basis production: wave -> m-half mh (coeffs wave-uniform/SGPR);
  // lane -> row (64 rows per wave-pair); each thread does BOTH il columns ----
  const int mh   = wave & 1;                        // m in [mh*8, mh*8+8)
  const int xrow = (wave >> 1) * 64 + lane;         // 0..127
  const int wsz  = (xrow >> 1) & 3;                 // XOR swizzle for this row
  // logical 16B slot = il*2 + mh; stored slot = logical ^ wsz
  const int aw0  = xrow * BK + ((mh ^ wsz) << 3);          // il=0
  const int aw1  = xrow * BK + (((2 + mh) ^ wsz) << 3);    // il=1

  float c1[8], c2[8], c3[8], c4[8], c5[8], c6[8], c7[8], c8[8];
  {
    const float* bch = bc + mh * 64;
    #pragma unroll
    for (int m = 0; m < 8; ++m) {
      c1[m] = rfl(bch[m*8+0]); c2[m] = rfl(bch[m*8+1]);
      c3[m] = rfl(bch[m*8+2]); c4[m] = rfl(bch[m*8+3]);
      c5[m] = rfl(bch[m*8+4]); c6[m] = rfl(bch[m*8+5]);
      c7[m] = rfl(bch[m*8+6]); c8[m] = rfl(bch[m*8+7]);
    }
  }

  const float LOG2E = 1.44269504088896340736f;
  const float LN2   = 0.69314718055994530942f;
#define BEVAL(xv, dst) do { \
    float xl2 = (xv) * LOG2E; \
    float x2 = (xv) * (xv), x3 = x2 * (xv), x4 = x2 * x2; \
    float ym[8]; \
    _Pragma("unroll") \
    for (int mi = 0; mi < 8; ++mi) { \
      float e     = __builtin_amdgcn_exp2f(c3[mi] * xl2); \
      float inner = e - 1.0f; \
      float p     = __builtin_amdgcn_exp2f(c4[mi] * __builtin_amdgcn_logf(inner)); \
      float u     = LN2 * __builtin_amdgcn_logf(1.0f + p); \
      float vv    = LN2 * __builtin_amdgcn_logf(1.0f + c2[mi] * u); \
      ym[mi] = c1[mi] * vv + c5[mi] * (xv) + c6[mi] * x2 + c7[mi] * x3 + c8[mi] * x4; \
    } \
    *(uint4*)(dst) = make_uint4(pkbf(ym[0], ym[1]), pkbf(ym[2], ym[3]), \
                                pkbf(ym[4], ym[5]), pkbf(ym[6], ym[7])); \
  } while (0)

#define BASIS(b, t) do { \
    float xv0 = Xs[(2 * (t) + 0) * BM + xrow]; \
    float xv1 = Xs[(2 * (t) + 1) * BM + xrow]; \
    BEVAL(xv0, &As[b][aw0]); \
    BEVAL(xv1, &As[b][aw1]); \
  } while (0)

  // ---- MFMA geometry: 4 waves as 2x2 grid of 64x128 wave-tiles ----
  const int wr = wave >> 1, wc = wave & 1;
  const int fm = lane & 15;
  const int fkswz = (((lane >> 4) ^ ((lane >> 1) & 3)) << 3);

  f32x4 acc[4][8] = {};

#define COMPUTE(b) do { \
    bf16x8 af[4], bfv[8]; \
    _Pragma("unroll") \
    for (int t2 = 0; t2 < 4; ++t2) \
      af[t2] = *(const bf16x8*)&As[b][(wr * 64 + t2 * 16 + fm) * BK + fkswz]; \
    _Pragma("unroll") \
    for (int u = 0; u < 8; ++u) \
      bfv[u] = *(const bf16x8*)&Bs[b][(wc * 128 + u * 16 + fm) * BK + fkswz]; \
    __builtin_amdgcn_s_setprio(1); \
    _Pragma("unroll") \
    for (int mt = 0; mt < 4; ++mt) \
      _Pragma("unroll") \
      for (int nt = 0; nt < 8; ++nt) \
        acc[mt][nt] = __builtin_amdgcn_mfma_f32_16x16x32_bf16(af[mt], bfv[nt], acc[mt][nt], 0, 0, 0); \
    __builtin_amdgcn_s_setprio(0); \
  } while (0)

  // ---- 2-phase pipeline, single schedule for all waves (no divergent roles:
  // round-4 showed duplicated paths spill acc past the 256-reg budget) ----
  STAGEB(0);
  __syncthreads();              // Xs ready + Bs[0] staged
  BASIS(0, 0);
  __syncthreads();              // As[0] ready
  for (int kt = 0; kt < NITER - 2; kt += 2) {
    STAGEB(1); COMPUTE(0); BASIS(1, kt + 1);
    __syncthreads();
    STAGEB(0); COMPUTE(1); BASIS(0, kt + 2);
    __syncthreads();
  }
  STAGEB(1); COMPUTE(0); BASIS(1, NITER - 1);
  __syncthreads();
  COMPUTE(1);

  // ---- epilogue: C/D layout col = lane&15, row = (lane>>4)*4 + reg ----
  const int colb = bn * BN + wc * 128 + fm;
  const int rowb = bm * BM + wr * 64 + (lane >> 4) * 4;
  float* out = P + (ATOMIC ? (size_t)0 : (size_t)ks * MN);
  #pragma unroll
  for (int mt = 0; mt < 4; ++mt) {
    #pragma unroll
    for (int nt = 0; nt < 8; ++nt) {
      #pragma unroll
      for (int j = 0; j < 4; ++j) {
        int row = rowb + mt * 16 + j;
        int col = colb + nt * 16;
        float vv = acc[mt][nt][j];
        if (ATOMIC) atomicAdd(out + (size_t)row * OUT_DIM + col, vv);
        else        out[(size_t)row * OUT_DIM + col] = vv;
      }
    }
  }
#undef STAGEB
#undef BEVAL
#undef BASIS
#undef COMPUTE
}

// ---------- phase 3: reduce split-K partials ----------
__global__ __launch_bounds__(256) void reduce_kernel(
    const float* __restrict__ P, float* __restrict__ out) {
  int i = blockIdx.x * 256 + threadIdx.x;
  const float4* p = (const float4*)P;
  float4 r = p[i];
  #pragma unroll
  for (int s = 1; s < SPLITK; ++s) {
    float4 v = p[i + (size_t)s * (MN / 4)];
    r.x += v.x; r.y += v.y; r.z += v.z; r.w += v.w;
  }
  ((float4*)out)[i] = r;
}

extern "C" void kernel_launch(void* const* d_in, const int* in_sizes, int n_in,
                              void* d_out, int out_size, void* d_ws, size_t ws_size,
                              hipStream_t stream) {
  const float* x      = (const float*)d_in[0];   // [4096][512]
  const float* coeffs = (const float*)d_in[1];   // [512][512][16]
  const float* b_coef = (const float*)d_in[2];   // [16][8]
  float* out = (float*)d_out;
  char*  ws  = (char*)d_ws;

  const size_t COEF_BYTES = (size_t)OUT_DIM * K_DIM * 2;   // 8 MiB
  ushort_t* coefb = (ushort_t*)ws;
  float* partials = (float*)(ws + COEF_BYTES);
  const size_t FULL = COEF_BYTES + (size_t)SPLITK * MN * 4;  // 72 MiB
  const bool use_atomic = (ws_size < FULL);   // deterministic per-session branch

  convert_coeffs_kernel<<<CONV_N4 / 256, 256, 0, stream>>>(coeffs, coefb);

  const int nblk = (B_DIM / BM) * (OUT_DIM / BN) * SPLITK;   // 32*2*8 = 512, 2/CU
  if (use_atomic) {
    hipMemsetAsync(d_out, 0, (size_t)MN * 4, stream);
    gemm_kernel<1><<<nblk, 256, 0, stream>>>(x, coefb, b_coef, out);
  } else {
    gemm_kernel<0><<<nblk, 256, 0, stream>>>(x, coefb, b_coef, partials);
    reduce_kernel<<<MN / 4 / 256, 256, 0, stream>>>(partials, out);
  }
}

// Round 7
// 135.302 us; speedup vs baseline: 1.1411x; 1.1411x over previous
//
#include <hip/hip_runtime.h>
#include <hip/hip_bf16.h>
#include <stdint.h>

#define B_DIM   4096
#define IN_DIM  512
#define OUT_DIM 512
#define M_DIM   16
#define K_DIM   (IN_DIM * M_DIM)     // 8192
#define MN      (B_DIM * OUT_DIM)    // 2097152

typedef unsigned short ushort_t;
typedef __attribute__((ext_vector_type(8))) __bf16 bf16x8;
typedef __attribute__((ext_vector_type(2))) __bf16 bf16x2;
typedef __attribute__((ext_vector_type(4))) float  f32x4;

__device__ __forceinline__ ushort_t f2bf(float f) {
  union { float f; uint32_t u; } v; v.f = f;
  uint32_t u = v.u + 0x7fffu + ((v.u >> 16) & 1u);   // RNE
  return (ushort_t)(u >> 16);
}

// pack two floats -> one u32 of 2 x bf16 (compiler emits v_cvt_pk_bf16_f32)
__device__ __forceinline__ uint32_t pkbf(float lo, float hi) {
  union { bf16x2 h; uint32_t u; } v;
  v.h[0] = (__bf16)lo; v.h[1] = (__bf16)hi;
  return v.u;
}

// force a wave-uniform float into an SGPR
__device__ __forceinline__ float rfl(float f) {
  union { float f; int i; } v; v.f = f;
  v.i = __builtin_amdgcn_readfirstlane(v.i);
  return v.f;
}

// ---------- phase 1: coeffs fp32 -> bf16 (layout [OUT][IN][M] == B^T [N][K]) ----------
#define CONV_N4 (OUT_DIM * K_DIM / 4)
__global__ __launch_bounds__(256) void convert_coeffs_kernel(
    const float* __restrict__ src, ushort_t* __restrict__ dst) {
  int i = blockIdx.x * 256 + threadIdx.x;
  float4 v = ((const float4*)src)[i];
  ushort4 o;
  o.x = f2bf(v.x); o.y = f2bf(v.y); o.z = f2bf(v.z); o.w = f2bf(v.w);
  ((ushort4*)dst)[i] = o;
}

// ---------- phase 2: FUSED basis+GEMM, counted-vmcnt pipeline (T3/T4) ----------
#define BM 128
#define BN 512
#define BK 32                 // = 2 input-columns x 16 m
#define SPLITK 8
#define KC (K_DIM / SPLITK)   // 1024
#define NITER (KC / BK)       // 32 K-steps
#define XCOLS (KC / M_DIM)    // 64 x-columns per block
#define XPAD  129             // row-dim pad for conflict-free reads

#define GLD16(g, l) \
  __builtin_amdgcn_global_load_lds((const __attribute__((address_space(1))) void*)(g), \
                                   (__attribute__((address_space(3))) void*)(l), 16, 0, 0)

// counted waits + raw barrier, with sched_barrier pins (rule #18 / m152 discipline)
#define VMW_LGKM(N) do { \
    asm volatile("s_waitcnt vmcnt(" #N ") lgkmcnt(0)" ::: "memory"); \
    __builtin_amdgcn_sched_barrier(0); } while (0)
#define RAW_BAR() do { \
    __builtin_amdgcn_s_barrier(); \
    __builtin_amdgcn_sched_barrier(0); } while (0)

template <int ATOMIC>
__global__ __launch_bounds__(512, 2) void gemm_kernel(
    const float* __restrict__ x,      // [B_DIM][IN_DIM] fp32
    const ushort_t* __restrict__ Bt,  // coeffs bf16 [OUT_DIM][K_DIM]
    const float* __restrict__ bc,     // [16][8]
    float* __restrict__ P) {          // partials [SPLITK][B][OUT] or out
  // LDS: As dbuf 16K + Bs TRIBUF 96K + Xs 32.25K = 144.25 KiB (1 block/CU)
  __shared__ __align__(16) ushort_t As[2][BM * BK];
  __shared__ __align__(16) ushort_t Bs[3][BN * BK];
  __shared__ __align__(16) float    Xs[XCOLS * XPAD];
  const int tid  = threadIdx.x;
  const int wave = tid >> 6;
  const int lane = tid & 63;
  const int wgid = blockIdx.x;
  const int ks = wgid & 7, bm = wgid >> 3;   // same-ks blocks adjacent -> same XCD

  // ---- x-tile staging (one-time): coalesced float4 loads -> transposed LDS ----
  {
    const int r = tid >> 2, q = tid & 3;
    const float4* xrow = (const float4*)(x + (size_t)(bm * BM + r) * IN_DIM + ks * XCOLS);
    #pragma unroll
    for (int j = 0; j < 4; ++j) {
      float4 v = xrow[q * 4 + j];
      Xs[(q * 16 + j * 4 + 0) * XPAD + r] = v.x;
      Xs[(q * 16 + j * 4 + 1) * XPAD + r] = v.y;
      Xs[(q * 16 + j * 4 + 2) * XPAD + r] = v.z;
      Xs[(q * 16 + j * 4 + 3) * XPAD + r] = v.w;
    }
  }

  // ---- B staging: global_load_lds linear dest, pre-swizzled source slot ----
  const int srow = wave * 16 + (lane >> 2);
  const int scol = (((lane & 3) ^ ((lane >> 3) & 3)) * 8);
  const ushort_t* Bg0 = Bt + (size_t)srow * K_DIM + ks * KC + scol;
  const ushort_t* Bg1 = Bg0 + (size_t)128 * K_DIM;
  const ushort_t* Bg2 = Bg0 + (size_t)256 * K_DIM;
  const ushort_t* Bg3 = Bg0 + (size_t)384 * K_DIM;
  const int bofs0 = (wave * 16) * BK;
  const int bofs1 = (128 + wave * 16) * BK;
  const int bofs2 = (256 + wave * 16) * BK;
  const int bofs3 = (384 + wave * 16) * BK;
  ushort_t* const BsBase = &Bs[0][0];

  // lb: wave-uniform LDS buffer index (scalar) -> dest stays wave-uniform
#define STAGEB(lb) do { \
    ushort_t* bb = BsBase + (lb) * (BN * BK); \
    GLD16(Bg0, bb + bofs0); GLD16(Bg1, bb + bofs1); \
    GLD16(Bg2, bb + bofs2); GLD16(Bg3, bb + bofs3); \
    Bg0 += BK; Bg1 += BK; Bg2 += BK; Bg3 += BK; } while (0)

  // ---- basis production: thread -> (row, i_local, m-half), half wave-uniform ----
  const int half = wave & 1;                       // m in [half*8, half*8+8)
  const int arow = (wave >> 1) * 32 + (lane >> 1); // 0..127
  const int il   = lane & 1;                       // which of 2 input cols in BK
  const int aslot = ((il * 2 + half) ^ ((lane >> 2) & 3));  // XOR-swizzled 16B slot
  const int awe   = arow * BK + aslot * 8;
  const int xbase = il * XPAD + arow;              // Xs[(il+2t)*XPAD + arow]

  float c1[8], c2[8], c3[8], c4[8], c5[8], c6[8], c7[8], c8[8];
  {
    const float* bch = bc + half * 64;
    #pragma unroll
    for (int m = 0; m < 8; ++m) {
      c1[m] = rfl(bch[m*8+0]); c2[m] = rfl(bch[m*8+1]);
      c3[m] = rfl(bch[m*8+2]); c4[m] = rfl(bch[m*8+3]);
      c5[m] = rfl(bch[m*8+4]); c6[m] = rfl(bch[m*8+5]);
      c7[m] = rfl(bch[m*8+6]); c8[m] = rfl(bch[m*8+7]);
    }
  }

  const float LOG2E = 1.44269504088896340736f;
  const float LN2   = 0.69314718055994530942f;
#define BASIS(pa, t) do { \
    float xv = Xs[xbase + 2 * XPAD * (t)]; \
    float xl2 = xv * LOG2E; \
    float x2 = xv * xv, x3 = x2 * xv, x4 = x2 * x2; \
    float ym[8]; \
    _Pragma("unroll") \
    for (int mi = 0; mi < 8; ++mi) { \
      float e     = __builtin_amdgcn_exp2f(c3[mi] * xl2); \
      float inner = e - 1.0f; \
      float p     = __builtin_amdgcn_exp2f(c4[mi] * __builtin_amdgcn_logf(inner)); \
      float u     = LN2 * __builtin_amdgcn_logf(1.0f + p); \
      float vv    = LN2 * __builtin_amdgcn_logf(1.0f + c2[mi] * u); \
      ym[mi] = c1[mi] * vv + c5[mi] * xv + c6[mi] * x2 + c7[mi] * x3 + c8[mi] * x4; \
    } \
    *(uint4*)((pa) + awe) = make_uint4(pkbf(ym[0], ym[1]), pkbf(ym[2], ym[3]), \
                                       pkbf(ym[4], ym[5]), pkbf(ym[6], ym[7])); \
  } while (0)

  // ---- MFMA geometry: 8 waves as 2x4 grid of 64x128 wave-tiles ----
  const int wr = wave >> 2, wc = wave & 3;
  const int fm = lane & 15;
  const int fkswz = (((lane >> 4) ^ ((lane >> 1) & 3)) << 3);

  f32x4 acc[4][8] = {};

#define COMPUTE(pa, lb) do { \
    const ushort_t* bb = BsBase + (lb) * (BN * BK); \
    bf16x8 af[4], bfv[8]; \
    _Pragma("unroll") \
    for (int t2 = 0; t2 < 4; ++t2) \
      af[t2] = *(const bf16x8*)((pa) + (wr * 64 + t2 * 16 + fm) * BK + fkswz); \
    _Pragma("unroll") \
    for (int u = 0; u < 8; ++u) \
      bfv[u] = *(const bf16x8*)(bb + (wc * 128 + u * 16 + fm) * BK + fkswz); \
    __builtin_amdgcn_s_setprio(1); \
    _Pragma("unroll") \
    for (int mt = 0; mt < 4; ++mt) \
      _Pragma("unroll") \
      for (int nt = 0; nt < 8; ++nt) \
        acc[mt][nt] = __builtin_amdgcn_mfma_f32_16x16x32_bf16(af[mt], bfv[nt], acc[mt][nt], 0, 0, 0); \
    __builtin_amdgcn_s_setprio(0); \
  } while (0)

  // ---- pipeline: Bs tri-buffered, loads stay in flight ~2 K-steps; barrier
  // drains lgkm only + counted vmcnt(4) (batch t+1 retired, t+2 in flight) ----
  STAGEB(0); STAGEB(1);
  __syncthreads();              // prologue: Xs + Bs[0..1] all visible (full drain, once)
  ushort_t* pAc = &As[0][0];    // compute buffer (As[t&1])
  ushort_t* pAp = &As[1][0];    // produce buffer (As[(t+1)&1])
  BASIS(pAc, 0);
  VMW_LGKM(0); RAW_BAR();       // As[0] visible

  int lb = 0, lbN = 2;
  for (int t = 0; t < NITER - 2; ++t) {
    STAGEB(lbN);                // batch t+2 -> Bs[(t+2)%3]
    BASIS(pAp, t + 1);          // As[(t+1)&1], VALU hides load latency
    COMPUTE(pAc, lb);           // As[t&1] x Bs[t%3]
    VMW_LGKM(4); RAW_BAR();     // batch t+1 retired in every wave, then barrier
    lb  = (lb  == 2) ? 0 : lb  + 1;
    lbN = (lbN == 2) ? 0 : lbN + 1;
    ushort_t* tmp = pAc; pAc = pAp; pAp = tmp;
  }
  // t = NITER-2 (no more staging)
  BASIS(pAp, NITER - 1);
  COMPUTE(pAc, lb);             // lb == (NITER-2)%3 == 0
  VMW_LGKM(0); RAW_BAR();
  // t = NITER-1
  COMPUTE(pAp, 1);              // Bs[(NITER-1)%3] == 1

  // ---- epilogue: C/D layout col = lane&15, row = (lane>>4)*4 + reg ----
  const int colb = wc * 128 + fm;
  const int rowb = bm * BM + wr * 64 + (lane >> 4) * 4;
  float* out = P + (ATOMIC ? (size_t)0 : (size_t)ks * MN);
  #pragma unroll
  for (int mt = 0; mt < 4; ++mt) {
    #pragma unroll
    for (int nt = 0; nt < 8; ++nt) {
      #pragma unroll
      for (int j = 0; j < 4; ++j) {
        int row = rowb + mt * 16 + j;
        int col = colb + nt * 16;
        float vv = acc[mt][nt][j];
        if (ATOMIC) atomicAdd(out + (size_t)row * OUT_DIM + col, vv);
        else        out[(size_t)row * OUT_DIM + col] = vv;
      }
    }
  }
#undef STAGEB
#undef BASIS
#undef COMPUTE
}

// ---------- phase 3: reduce split-K partials ----------
__global__ __launch_bounds__(256) void reduce_kernel(
    const float* __restrict__ P, float* __restrict__ out) {
  int i = blockIdx.x * 256 + threadIdx.x;
  const float4* p = (const float4*)P;
  float4 r = p[i];
  #pragma unroll
  for (int s = 1; s < SPLITK; ++s) {
    float4 v = p[i + (size_t)s * (MN / 4)];
    r.x += v.x; r.y += v.y; r.z += v.z; r.w += v.w;
  }
  ((float4*)out)[i] = r;
}

extern "C" void kernel_launch(void* const* d_in, const int* in_sizes, int n_in,
                              void* d_out, int out_size, void* d_ws, size_t ws_size,
                              hipStream_t stream) {
  const float* x      = (const float*)d_in[0];   // [4096][512]
  const float* coeffs = (const float*)d_in[1];   // [512][512][16]
  const float* b_coef = (const float*)d_in[2];   // [16][8]
  float* out = (float*)d_out;
  char*  ws  = (char*)d_ws;

  const size_t COEF_BYTES = (size_t)OUT_DIM * K_DIM * 2;   // 8 MiB
  ushort_t* coefb = (ushort_t*)ws;
  float* partials = (float*)(ws + COEF_BYTES);
  const size_t FULL = COEF_BYTES + (size_t)SPLITK * MN * 4;  // 72 MiB
  const bool use_atomic = (ws_size < FULL);   // deterministic per-session branch

  convert_coeffs_kernel<<<CONV_N4 / 256, 256, 0, stream>>>(coeffs, coefb);

  const int nblk = (B_DIM / BM) * SPLITK;   // 32 x 8 = 256 blocks, 1/CU
  if (use_atomic) {
    hipMemsetAsync(d_out, 0, (size_t)MN * 4, stream);
    gemm_kernel<1><<<nblk, 512, 0, stream>>>(x, coefb, b_coef, out);
  } else {
    gemm_kernel<0><<<nblk, 512, 0, stream>>>(x, coefb, b_coef, partials);
    reduce_kernel<<<MN / 4 / 256, 256, 0, stream>>>(partials, out);
  }
}